// Round 14
// baseline (624.530 us; speedup 1.0000x reference)
//
#include <hip/hip_runtime.h>
#include <stdint.h>

#define BB 4
#define SS 1024
#define DD 1024
#define HH 16

typedef __attribute__((ext_vector_type(8))) __bf16 bf16x8;
typedef __attribute__((ext_vector_type(4))) __bf16 bf16x4;
typedef __attribute__((ext_vector_type(4))) float f32x4;

__device__ __forceinline__ unsigned short f2bf(float f) {
  union { float ff; uint32_t u; } a; a.ff = f;
  uint32_t r = a.u + 0x7fffu + ((a.u >> 16) & 1u);
  return (unsigned short)(r >> 16);
}

__device__ __forceinline__ float bf2f(unsigned short u) {
  union { uint32_t uu; float ff; } a; a.uu = ((uint32_t)u) << 16;
  return a.ff;
}

__device__ __forceinline__ f32x4 mfma16(bf16x8 a, bf16x8 b, f32x4 c) {
  return __builtin_amdgcn_mfma_f32_16x16x32_bf16(a, b, c, 0, 0, 0);
}

// pack two fp32 -> packed bf16x2 (lo = a, hi = b), RNE
__device__ __forceinline__ uint32_t cvtpk(float a, float b) {
  uint32_t r;
  asm("v_cvt_pk_bf16_f32 %0, %1, %2" : "=v"(r) : "v"(a), "v"(b));
  return r;
}

// global -> LDS direct copy, 16B per lane; LDS dest is wave-uniform base + lane*16
__device__ __forceinline__ void async16(const unsigned short* g, unsigned short* l) {
  __builtin_amdgcn_global_load_lds(
      (__attribute__((address_space(1))) void*)(g),
      (__attribute__((address_space(3))) void*)(l), 16u, 0, 0u);
}

// nontemporal 16B store — must use clang ext_vector_type, not HIP float4 class
__device__ __forceinline__ void nt_store4(float* p, f32x4 v) {
  __builtin_nontemporal_store(v, (f32x4*)p);
}

// ---------- W (K x N fp32) -> Wt (N x K bf16), z selects which of Q/K/V ----------
__global__ __launch_bounds__(256) void wtrans_kernel(const float* __restrict__ Wq,
                                                     const float* __restrict__ Wk,
                                                     const float* __restrict__ Wv,
                                                     unsigned short* __restrict__ Wtq,
                                                     unsigned short* __restrict__ Wtk,
                                                     unsigned short* __restrict__ Wtv) {
  __shared__ unsigned short t[64][65];
  const int z = blockIdx.z;
  const float* W = (z == 0) ? Wq : (z == 1) ? Wk : Wv;
  unsigned short* Wt = (z == 0) ? Wtq : (z == 1) ? Wtk : Wtv;
  const int k0 = blockIdx.x * 64, n0 = blockIdx.y * 64;
  const int c = threadIdx.x & 63, r0 = threadIdx.x >> 6;
#pragma unroll
  for (int i = 0; i < 16; ++i) {
    int r = i * 4 + r0;
    t[r][c] = f2bf(W[(size_t)(k0 + r) * DD + n0 + c]);
  }
  __syncthreads();
#pragma unroll
  for (int i = 0; i < 16; ++i) {
    int n = i * 4 + r0;
    Wt[(size_t)(n0 + n) * DD + k0 + c] = t[c][n];
  }
}

// ---------- LayerNorm (fp32 math) -> bf16 ----------
__global__ __launch_bounds__(256) void ln_kernel(const float* __restrict__ X,
                                                 const float* __restrict__ gamma,
                                                 const float* __restrict__ beta,
                                                 unsigned short* __restrict__ Xn) {
  const int row = blockIdx.x;
  const int tid = threadIdx.x;
  const float* xr = X + (size_t)row * DD;
  float4 v = ((const float4*)xr)[tid];
  float s = v.x + v.y + v.z + v.w;
  float s2 = v.x * v.x + v.y * v.y + v.z * v.z + v.w * v.w;
#pragma unroll
  for (int off = 1; off < 64; off <<= 1) {
    s += __shfl_xor(s, off);
    s2 += __shfl_xor(s2, off);
  }
  __shared__ float red[8];
  const int wv = tid >> 6, lane = tid & 63;
  if (lane == 0) { red[wv] = s; red[4 + wv] = s2; }
  __syncthreads();
  s = red[0] + red[1] + red[2] + red[3];
  s2 = red[4] + red[5] + red[6] + red[7];
  const float mu = s * (1.0f / DD);
  const float rs = rsqrtf(s2 * (1.0f / DD) - mu * mu + 1e-5f);
  float4 g = ((const float4*)gamma)[tid];
  float4 bt = ((const float4*)beta)[tid];
  ushort4 o;
  o.x = f2bf((v.x - mu) * rs * g.x + bt.x);
  o.y = f2bf((v.y - mu) * rs * g.y + bt.y);
  o.z = f2bf((v.z - mu) * rs * g.z + bt.z);
  o.w = f2bf((v.w - mu) * rs * g.w + bt.w);
  ((ushort4*)(Xn + (size_t)row * DD))[tid] = o;
}

// ---------- QKV GEMM: C = Xn (M x K) * Wt^T (Wt is N x K), 128x128 tile ----------
// Double-buffered staging: stage kt+32 before computing kt, ONE barrier per K-step.
__global__ __launch_bounds__(256) void gemm_qkv_kernel(
    const unsigned short* __restrict__ Xn,
    const unsigned short* __restrict__ Wtq, const unsigned short* __restrict__ Wtk,
    const unsigned short* __restrict__ Wtv,
    const float* __restrict__ bq, const float* __restrict__ bk, const float* __restrict__ bv,
    unsigned short* __restrict__ Qb, unsigned short* __restrict__ Kb,
    unsigned short* __restrict__ Vt) {
  // union: dbuf [sA|sB]x2 (32 KB) during K-loop, sC 128x136 (34.8 KB) in epilogue
  __shared__ __align__(16) unsigned short smem[128 * 136];
  unsigned short* const sA0 = smem;
  unsigned short* const sB0 = smem + 4096;
  unsigned short* const sA1 = smem + 8192;
  unsigned short* const sB1 = smem + 12288;
  const int z = blockIdx.z;
  const unsigned short* Wt = (z == 0) ? Wtq : (z == 1) ? Wtk : Wtv;
  const float* bias = (z == 0) ? bq : (z == 1) ? bk : bv;
  const int tid = threadIdx.x;
  const int lane = tid & 63, wv = tid >> 6;
  const int quad = lane >> 4, l16 = lane & 15;
  const int m0 = blockIdx.x * 128, n0 = blockIdx.y * 128;
  const int wm = (wv & 1) * 64, wn = (wv >> 1) * 64;

  f32x4 acc[4][4];
#pragma unroll
  for (int i = 0; i < 4; ++i)
#pragma unroll
    for (int j = 0; j < 4; ++j) acc[i][j] = (f32x4){0.f, 0.f, 0.f, 0.f};

  auto stage = [&](int kt, unsigned short* sA, unsigned short* sB) {
#pragma unroll
    for (int it = 0; it < 2; ++it) {
      const int c = it * 256 + tid;
      const int row = c >> 2, kc = c & 3;
      async16(Xn + (size_t)(m0 + row) * DD + kt + kc * 8, &sA[(it * 256 + wv * 64) * 8]);
      async16(Wt + (size_t)(n0 + row) * DD + kt + kc * 8, &sB[(it * 256 + wv * 64) * 8]);
    }
  };

  stage(0, sA0, sB0);
  __syncthreads();

  for (int kt = 0; kt < DD; kt += 32) {
    const int par = (kt >> 5) & 1;
    unsigned short* const sA = par ? sA1 : sA0;
    unsigned short* const sB = par ? sB1 : sB0;
    if (kt + 32 < DD) stage(kt + 32, par ? sA0 : sA1, par ? sB0 : sB1);
    bf16x8 af[4], bfr[4];
#pragma unroll
    for (int i = 0; i < 4; ++i) af[i] = *(const bf16x8*)&sA[(wm + i * 16 + l16) * 32 + quad * 8];
#pragma unroll
    for (int j = 0; j < 4; ++j) bfr[j] = *(const bf16x8*)&sB[(wn + j * 16 + l16) * 32 + quad * 8];
#pragma unroll
    for (int i = 0; i < 4; ++i)
#pragma unroll
      for (int j = 0; j < 4; ++j) acc[i][j] = mfma16(af[i], bfr[j], acc[i][j]);
    __syncthreads();
  }

  if (z < 2) {
    // stage C tile (bf16) in padded LDS, then vectorized 16B stores
    unsigned short* sC = smem;  // 128 x 136
#pragma unroll
    for (int i = 0; i < 4; ++i) {
      const int lr0 = wm + i * 16 + quad * 4;
#pragma unroll
      for (int j = 0; j < 4; ++j) {
        const int lc = wn + j * 16 + l16;
        const float bb = bias[n0 + lc];
#pragma unroll
        for (int r = 0; r < 4; ++r) sC[(lr0 + r) * 136 + lc] = f2bf(acc[i][j][r] + bb);
      }
    }
    __syncthreads();
    unsigned short* Out = (z == 0) ? Qb : Kb;
    const int rr = tid >> 4, c8 = (tid & 15) * 8;
#pragma unroll
    for (int it = 0; it < 8; ++it) {
      const int row = it * 16 + rr;
      *(uint4*)&Out[(size_t)(m0 + row) * DD + n0 + c8] = *(const uint4*)&sC[row * 136 + c8];
    }
  } else {
    // transposed staging: sC[dv-local][s-local], then 256B-contiguous row stores
    unsigned short* sC = smem;  // 128 x 136
#pragma unroll
    for (int i = 0; i < 4; ++i) {
      const int lr0 = wm + i * 16 + quad * 4;   // s-local
#pragma unroll
      for (int j = 0; j < 4; ++j) {
        const int lc = wn + j * 16 + l16;       // dv-local (n)
        const float bb = bias[n0 + lc];
#pragma unroll
        for (int r = 0; r < 4; ++r) sC[lc * 136 + lr0 + r] = f2bf(acc[i][j][r] + bb);
      }
    }
    __syncthreads();
    const int b = m0 >> 10, s0 = m0 & 1023;
    const int rr = tid >> 4, c8 = (tid & 15) * 8;
#pragma unroll
    for (int it = 0; it < 8; ++it) {
      const int row = it * 16 + rr;  // dv-local
      const int n = n0 + row;
      unsigned short* dst =
          &Vt[((size_t)((b * HH + (n >> 6)) * 64 + (n & 63))) * SS + s0 + c8];
      *(uint4*)dst = *(const uint4*)&sC[row * 136 + c8];
    }
  }
}

// ---------- fused attention: per (b,h,q-tile 64) ----------
// *** MEASUREMENT BUILD: entire body repeated REPS=4x inside the dispatch. ***
// Pure function of inputs (no atomics) -> each rep writes identical outputs;
// dur_us Delta vs the 1x build = 3*T_attn, and the 4x dispatch surfaces in the
// rocprof top-5 with full counters (first direct look at attn's MfmaUtil/BW).
__global__ __launch_bounds__(256) void attn_kernel(
    const unsigned short* __restrict__ Qb, const unsigned short* __restrict__ Kb,
    const unsigned short* __restrict__ Vt, const float* __restrict__ X,
    const int* __restrict__ lens, float* __restrict__ seq_out,
    float* __restrict__ attn_out) {
  __shared__ __align__(16) unsigned short smem[4 * 64 * 64];  // 32 KB
  unsigned short* const sK0 = smem;            // 8 KB  K buf 0
  unsigned short* const sK1 = smem + 4096;     // 8 KB  K buf 1
  unsigned short* const sV0 = smem + 8192;     // 8 KB  Q tile, then V buf 0
  unsigned short* const sV1 = smem + 12288;    // 8 KB  V buf 1

  const int tid = threadIdx.x;
  const int lane = tid & 63, wv = tid >> 6;
  const int quad = lane >> 4, l16 = lane & 15;
  const int h = blockIdx.y, b = blockIdx.z;
  const int qt = (b & 2) ? (15 - (int)blockIdx.x) : (int)blockIdx.x;
  const int q0 = qt * 64;
  const int len = lens[b];
  const int KE = min(q0 + 64, len);
  const int NKT = (KE + 63) >> 6;
  const float SCL = 0.1803368801111204f;  // 0.125 * log2(e)
  const int s7 = l16 & 7;                 // row&7 for 64-short rows (row = ..+l16)

  auto stageK = [&](int k0, unsigned short* dst) {
#pragma unroll
    for (int it = 0; it < 2; ++it) {
      const int c = it * 256 + tid;
      const int row = c >> 3, ch = (c & 7) ^ (row & 7);
      async16(Kb + (size_t)(b * SS + k0 + row) * DD + h * 64 + ch * 8,
              &dst[(it * 256 + wv * 64) * 8]);
    }
  };
  auto stageV = [&](int k0, unsigned short* dst) {
#pragma unroll
    for (int it = 0; it < 2; ++it) {
      const int c = it * 256 + tid;
      const int row = c >> 3, ch = (c & 7) ^ (row & 7);  // row = dv 0..63, 8 chunks
      async16(Vt + ((size_t)((b * HH + h) * 64 + row)) * SS + k0 + ch * 8,
              &dst[(it * 256 + wv * 64) * 8]);
    }
  };

  const size_t abase = (size_t)(b * HH + h) * SS * SS;
  float* const arow = attn_out + abase + (size_t)(q0 + wv * 16 + l16) * SS;

  for (int rep = 0; rep < 4; ++rep) {
    // ---- prologue: stage Q (into sV0) and K tile 0 ----
#pragma unroll
    for (int it = 0; it < 2; ++it) {
      const int c = it * 256 + tid;
      const int row = c >> 3, ch = (c & 7) ^ (row & 7);
      async16(Qb + (size_t)(b * SS + q0 + row) * DD + h * 64 + ch * 8,
              &sV0[(it * 256 + wv * 64) * 8]);
    }
    stageK(0, sK0);
    __syncthreads();

    bf16x8 qf[2];
#pragma unroll
    for (int dd = 0; dd < 2; ++dd)
      qf[dd] = *(const bf16x8*)
          &sV0[(wv * 16 + l16) * 64 + ((dd * 4 + quad) ^ s7) * 8];

    // ---- pass 1: denominators ----
    float lsum = 0.f;
    int par = 0;

    for (int kt = 0; kt < NKT; ++kt) {
      const int k0 = kt * 64;
      const int nxt = par ^ 1;
      unsigned short* const Kcur = par ? sK1 : sK0;
      if (kt + 1 < NKT) {
        stageK((kt + 1) * 64, nxt ? sK1 : sK0);
      } else {  // prefetch pass-2 tile 0
        stageK(0, nxt ? sK1 : sK0);
        stageV(0, nxt ? sV1 : sV0);
      }
      const bool edge = (kt == qt) || (k0 + 64 > len);
      const int qq = q0 + wv * 16 + l16;
#pragma unroll
      for (int j = 0; j < 4; ++j) {
        const bf16x8 kf0 = *(const bf16x8*)&Kcur[(j * 16 + l16) * 64 + ((0 + quad) ^ s7) * 8];
        const bf16x8 kf1 = *(const bf16x8*)&Kcur[(j * 16 + l16) * 64 + ((4 + quad) ^ s7) * 8];
        const int kb = k0 + j * 16 + quad * 4;
        f32x4 sc = (f32x4){0.f, 0.f, 0.f, 0.f};
        __builtin_amdgcn_s_setprio(1);
        sc = mfma16(kf0, qf[0], sc);
        sc = mfma16(kf1, qf[1], sc);
        __builtin_amdgcn_s_setprio(0);
#pragma unroll
        for (int r = 0; r < 4; ++r) {
          float sv = sc[r] * SCL;
          if (edge && ((kb + r > qq) || (kb + r >= len))) sv = -1e30f;
          lsum += __builtin_amdgcn_exp2f(sv);
        }
      }
      __syncthreads();
      par = nxt;
    }

    float linv;
    {
      float l = lsum;
      l += __shfl_xor(l, 16);
      l += __shfl_xor(l, 32);
      linv = 1.0f / l;
    }

    // ---- pass 2 ----
    f32x4 oacc[4];
#pragma unroll
    for (int jv = 0; jv < 4; ++jv) oacc[jv] = (f32x4){0.f, 0.f, 0.f, 0.f};

    for (int kt = 0; kt < NKT; ++kt) {
      const int k0 = kt * 64;
      const int nxt = par ^ 1;
      unsigned short* const Kcur = par ? sK1 : sK0;
      unsigned short* const Vcur = par ? sV1 : sV0;
      if (kt + 1 < NKT) {
        stageK((kt + 1) * 64, nxt ? sK1 : sK0);
        stageV((kt + 1) * 64, nxt ? sV1 : sV0);
      }
      const bool edge = (kt == qt) || (k0 + 64 > len);
      const int qq = q0 + wv * 16 + l16;

      uint32_t afw[2][4];  // [kk][word] — PV A-fragment words, built in-register
#pragma unroll
      for (int j = 0; j < 4; ++j) {
        const bf16x8 kf0 = *(const bf16x8*)&Kcur[(j * 16 + l16) * 64 + ((0 + quad) ^ s7) * 8];
        const bf16x8 kf1 = *(const bf16x8*)&Kcur[(j * 16 + l16) * 64 + ((4 + quad) ^ s7) * 8];
        const int kb = k0 + j * 16 + quad * 4;
        f32x4 sc = (f32x4){0.f, 0.f, 0.f, 0.f};
        __builtin_amdgcn_s_setprio(1);
        sc = mfma16(kf0, qf[0], sc);
        sc = mfma16(kf1, qf[1], sc);
        __builtin_amdgcn_s_setprio(0);
        f32x4 p;
#pragma unroll
        for (int r = 0; r < 4; ++r) {
          float sv = sc[r] * SCL;
          if (edge && ((kb + r > qq) || (kb + r >= len))) sv = -1e30f;
          p[r] = __builtin_amdgcn_exp2f(sv) * linv;
        }
        nt_store4(arow + kb, p);
        afw[j >> 1][(j & 1) * 2 + 0] = cvtpk(p[0], p[1]);
        afw[j >> 1][(j & 1) * 2 + 1] = cvtpk(p[2], p[3]);
      }

      // PV: O += P (16x64) * V (64x64), per wave; P already in registers.
#pragma unroll
      for (int kk = 0; kk < 2; ++kk) {
        union { bf16x8 v8; bf16x4 v4[2]; } vfu[4];
        const int g1 = kk * 4 + (quad >> 1);       // kv chunk of run 1 (0..7)
        const int boff = (quad & 1) * 8;           // byte offset within chunk
#pragma unroll
        for (int jv = 0; jv < 4; ++jv) {
          const char* rowp = (const char*)(Vcur + (jv * 16 + l16) * 64);
          vfu[jv].v4[0] = *(const bf16x4*)(rowp + ((g1 ^ s7) * 16 + boff));
          vfu[jv].v4[1] = *(const bf16x4*)(rowp + (((g1 + 2) ^ s7) * 16 + boff));
        }
        union { uint32_t w[4]; bf16x8 v8; } pu;
        pu.w[0] = afw[kk][0];
        pu.w[1] = afw[kk][1];
        pu.w[2] = afw[kk][2];
        pu.w[3] = afw[kk][3];
        __builtin_amdgcn_s_setprio(1);
#pragma unroll
        for (int jv = 0; jv < 4; ++jv) oacc[jv] = mfma16(pu.v8, vfu[jv].v8, oacc[jv]);
        __builtin_amdgcn_s_setprio(0);
      }
      __syncthreads();
      par = nxt;
    }

    // zero-fill fully-masked column range [NKT*64, S)
    const int Z = SS - NKT * 64;
    if (Z > 0) {
      const int rr0 = tid >> 3;
      const int cf = (tid & 7) * 4;
      const f32x4 zz = (f32x4){0.f, 0.f, 0.f, 0.f};
      for (int rr = rr0; rr < 64; rr += 32) {
        float* dst = attn_out + abase + (size_t)(q0 + rr) * SS + NKT * 64 + cf;
        for (int c8 = 0; c8 < (Z >> 5); ++c8) nt_store4(dst + c8 * 32, zz);
      }
    }

    // epilogue: stage O in LDS (fp32, reuse smem), then seq = x + O via float4
    __syncthreads();
    {
      float* sPf = (float*)smem + wv * 1024;  // 4 KB per wave, 16 KB total
#pragma unroll
      for (int jv = 0; jv < 4; ++jv)
#pragma unroll
        for (int r = 0; r < 4; ++r)
          sPf[(quad * 4 + r) * 64 + jv * 16 + l16] = oacc[jv][r];
      const int rr = lane >> 4, c4 = (lane & 15) * 4;
#pragma unroll
      for (int it = 0; it < 4; ++it) {
        const int lrow = it * 4 + rr;
        const size_t idx = (size_t)(b * SS + q0 + wv * 16 + lrow) * DD + h * 64 + c4;
        float4 o = *(const float4*)&sPf[lrow * 64 + c4];
        float4 x = *(const float4*)&X[idx];
        o.x += x.x; o.y += x.y; o.z += x.z; o.w += x.w;
        *(float4*)&seq_out[idx] = o;
      }
    }
    __syncthreads();  // epilogue LDS use must finish before next rep's staging
  }
}

extern "C" void kernel_launch(void* const* d_in, const int* in_sizes, int n_in,
                              void* d_out, int out_size, void* d_ws, size_t ws_size,
                              hipStream_t stream) {
  (void)in_sizes; (void)n_in; (void)out_size; (void)ws_size;
  const float* X     = (const float*)d_in[0];
  const int*   lens  = (const int*)d_in[3];
  const float* gamma = (const float*)d_in[4];
  const float* beta  = (const float*)d_in[5];
  const float* Wq    = (const float*)d_in[6];
  const float* bq    = (const float*)d_in[7];
  const float* Wk    = (const float*)d_in[8];
  const float* bk    = (const float*)d_in[9];
  const float* Wv    = (const float*)d_in[10];
  const float* bv    = (const float*)d_in[11];

  // workspace layout (38 MB total)
  char* ws = (char*)d_ws;
  unsigned short* Xn  = (unsigned short*)(ws);                      // 8 MB
  unsigned short* Qb  = (unsigned short*)(ws + ((size_t)8  << 20)); // 8 MB
  unsigned short* Kb  = (unsigned short*)(ws + ((size_t)16 << 20)); // 8 MB
  unsigned short* Vt  = (unsigned short*)(ws + ((size_t)24 << 20)); // 8 MB  (B*H*64, S)
  unsigned short* Wtq = (unsigned short*)(ws + ((size_t)32 << 20)); // 2 MB
  unsigned short* Wtk = (unsigned short*)(ws + ((size_t)34 << 20)); // 2 MB
  unsigned short* Wtv = (unsigned short*)(ws + ((size_t)36 << 20)); // 2 MB

  float* seq_out  = (float*)d_out;                         // (B,S,1024)
  float* attn_out = seq_out + (size_t)BB * SS * DD;        // (B,H,S,S)

  wtrans_kernel<<<dim3(16, 16, 3), 256, 0, stream>>>(Wq, Wk, Wv, Wtq, Wtk, Wtv);
  ln_kernel<<<dim3(BB * SS), 256, 0, stream>>>(X, gamma, beta, Xn);
  gemm_qkv_kernel<<<dim3(32, 8, 3), 256, 0, stream>>>(Xn, Wtq, Wtk, Wtv, bq, bk, bv, Qb, Kb, Vt);
  attn_kernel<<<dim3(16, HH, BB), 256, 0, stream>>>(Qb, Kb, Vt, X, lens, seq_out, attn_out);
}

// Round 15
// 571.278 us; speedup vs baseline: 1.0932x; 1.0932x over previous
//
#include <hip/hip_runtime.h>
#include <stdint.h>

#define BB 4
#define SS 1024
#define DD 1024
#define HH 16

typedef __attribute__((ext_vector_type(8))) __bf16 bf16x8;
typedef __attribute__((ext_vector_type(4))) __bf16 bf16x4;
typedef __attribute__((ext_vector_type(4))) float f32x4;

__device__ __forceinline__ unsigned short f2bf(float f) {
  union { float ff; uint32_t u; } a; a.ff = f;
  uint32_t r = a.u + 0x7fffu + ((a.u >> 16) & 1u);
  return (unsigned short)(r >> 16);
}

__device__ __forceinline__ float bf2f(unsigned short u) {
  union { uint32_t uu; float ff; } a; a.uu = ((uint32_t)u) << 16;
  return a.ff;
}

__device__ __forceinline__ f32x4 mfma16(bf16x8 a, bf16x8 b, f32x4 c) {
  return __builtin_amdgcn_mfma_f32_16x16x32_bf16(a, b, c, 0, 0, 0);
}

// pack two fp32 -> packed bf16x2 (lo = a, hi = b), RNE
__device__ __forceinline__ uint32_t cvtpk(float a, float b) {
  uint32_t r;
  asm("v_cvt_pk_bf16_f32 %0, %1, %2" : "=v"(r) : "v"(a), "v"(b));
  return r;
}

// global -> LDS direct copy, 16B per lane; LDS dest is wave-uniform base + lane*16
__device__ __forceinline__ void async16(const unsigned short* g, unsigned short* l) {
  __builtin_amdgcn_global_load_lds(
      (__attribute__((address_space(1))) void*)(g),
      (__attribute__((address_space(3))) void*)(l), 16u, 0, 0u);
}

// nontemporal 16B store — must use clang ext_vector_type, not HIP float4 class
__device__ __forceinline__ void nt_store4(float* p, f32x4 v) {
  __builtin_nontemporal_store(v, (f32x4*)p);
}

// ---------- W (K x N fp32) -> Wt (N x K bf16), z selects which of Q/K/V ----------
__global__ __launch_bounds__(256) void wtrans_kernel(const float* __restrict__ Wq,
                                                     const float* __restrict__ Wk,
                                                     const float* __restrict__ Wv,
                                                     unsigned short* __restrict__ Wtq,
                                                     unsigned short* __restrict__ Wtk,
                                                     unsigned short* __restrict__ Wtv) {
  __shared__ unsigned short t[64][65];
  const int z = blockIdx.z;
  const float* W = (z == 0) ? Wq : (z == 1) ? Wk : Wv;
  unsigned short* Wt = (z == 0) ? Wtq : (z == 1) ? Wtk : Wtv;
  const int k0 = blockIdx.x * 64, n0 = blockIdx.y * 64;
  const int c = threadIdx.x & 63, r0 = threadIdx.x >> 6;
#pragma unroll
  for (int i = 0; i < 16; ++i) {
    int r = i * 4 + r0;
    t[r][c] = f2bf(W[(size_t)(k0 + r) * DD + n0 + c]);
  }
  __syncthreads();
#pragma unroll
  for (int i = 0; i < 16; ++i) {
    int n = i * 4 + r0;
    Wt[(size_t)(n0 + n) * DD + k0 + c] = t[c][n];
  }
}

// ---------- LayerNorm (fp32 math) -> bf16 ----------
__global__ __launch_bounds__(256) void ln_kernel(const float* __restrict__ X,
                                                 const float* __restrict__ gamma,
                                                 const float* __restrict__ beta,
                                                 unsigned short* __restrict__ Xn) {
  const int row = blockIdx.x;
  const int tid = threadIdx.x;
  const float* xr = X + (size_t)row * DD;
  float4 v = ((const float4*)xr)[tid];
  float s = v.x + v.y + v.z + v.w;
  float s2 = v.x * v.x + v.y * v.y + v.z * v.z + v.w * v.w;
#pragma unroll
  for (int off = 1; off < 64; off <<= 1) {
    s += __shfl_xor(s, off);
    s2 += __shfl_xor(s2, off);
  }
  __shared__ float red[8];
  const int wv = tid >> 6, lane = tid & 63;
  if (lane == 0) { red[wv] = s; red[4 + wv] = s2; }
  __syncthreads();
  s = red[0] + red[1] + red[2] + red[3];
  s2 = red[4] + red[5] + red[6] + red[7];
  const float mu = s * (1.0f / DD);
  const float rs = rsqrtf(s2 * (1.0f / DD) - mu * mu + 1e-5f);
  float4 g = ((const float4*)gamma)[tid];
  float4 bt = ((const float4*)beta)[tid];
  ushort4 o;
  o.x = f2bf((v.x - mu) * rs * g.x + bt.x);
  o.y = f2bf((v.y - mu) * rs * g.y + bt.y);
  o.z = f2bf((v.z - mu) * rs * g.z + bt.z);
  o.w = f2bf((v.w - mu) * rs * g.w + bt.w);
  ((ushort4*)(Xn + (size_t)row * DD))[tid] = o;
}

// ---------- QKV GEMM: C = Xn (M x K) * Wt^T (Wt is N x K), 128x128 tile ----------
// *** MEASUREMENT BUILD: body repeated REPS=4x inside the dispatch. ***
// Pure function (reads Xn/Wt/bias, writes Qb/Kb/Vt deterministically) -> each rep
// writes identical outputs. Delta dur vs r10 = 3*T_gemm; the 4x dispatch surfaces
// in rocprof top-5 with counters if T_gemm > ~44us.
__global__ __launch_bounds__(256) void gemm_qkv_kernel(
    const unsigned short* __restrict__ Xn,
    const unsigned short* __restrict__ Wtq, const unsigned short* __restrict__ Wtk,
    const unsigned short* __restrict__ Wtv,
    const float* __restrict__ bq, const float* __restrict__ bk, const float* __restrict__ bv,
    unsigned short* __restrict__ Qb, unsigned short* __restrict__ Kb,
    unsigned short* __restrict__ Vt) {
  // union: dbuf [sA|sB]x2 (32 KB) during K-loop, sC 128x136 (34.8 KB) in epilogue
  __shared__ __align__(16) unsigned short smem[128 * 136];
  unsigned short* const sA0 = smem;
  unsigned short* const sB0 = smem + 4096;
  unsigned short* const sA1 = smem + 8192;
  unsigned short* const sB1 = smem + 12288;
  const int z = blockIdx.z;
  const unsigned short* Wt = (z == 0) ? Wtq : (z == 1) ? Wtk : Wtv;
  const float* bias = (z == 0) ? bq : (z == 1) ? bk : bv;
  const int tid = threadIdx.x;
  const int lane = tid & 63, wv = tid >> 6;
  const int quad = lane >> 4, l16 = lane & 15;
  const int m0 = blockIdx.x * 128, n0 = blockIdx.y * 128;
  const int wm = (wv & 1) * 64, wn = (wv >> 1) * 64;

  auto stage = [&](int kt, unsigned short* sA, unsigned short* sB) {
#pragma unroll
    for (int it = 0; it < 2; ++it) {
      const int c = it * 256 + tid;
      const int row = c >> 2, kc = c & 3;
      async16(Xn + (size_t)(m0 + row) * DD + kt + kc * 8, &sA[(it * 256 + wv * 64) * 8]);
      async16(Wt + (size_t)(n0 + row) * DD + kt + kc * 8, &sB[(it * 256 + wv * 64) * 8]);
    }
  };

  for (int rep = 0; rep < 4; ++rep) {
    f32x4 acc[4][4];
#pragma unroll
    for (int i = 0; i < 4; ++i)
#pragma unroll
      for (int j = 0; j < 4; ++j) acc[i][j] = (f32x4){0.f, 0.f, 0.f, 0.f};

    stage(0, sA0, sB0);
    __syncthreads();

    for (int kt = 0; kt < DD; kt += 32) {
      const int par = (kt >> 5) & 1;
      unsigned short* const sA = par ? sA1 : sA0;
      unsigned short* const sB = par ? sB1 : sB0;
      if (kt + 32 < DD) stage(kt + 32, par ? sA0 : sA1, par ? sB0 : sB1);
      bf16x8 af[4], bfr[4];
#pragma unroll
      for (int i = 0; i < 4; ++i) af[i] = *(const bf16x8*)&sA[(wm + i * 16 + l16) * 32 + quad * 8];
#pragma unroll
      for (int j = 0; j < 4; ++j) bfr[j] = *(const bf16x8*)&sB[(wn + j * 16 + l16) * 32 + quad * 8];
#pragma unroll
      for (int i = 0; i < 4; ++i)
#pragma unroll
        for (int j = 0; j < 4; ++j) acc[i][j] = mfma16(af[i], bfr[j], acc[i][j]);
      __syncthreads();
    }

    if (z < 2) {
      // stage C tile (bf16) in padded LDS, then vectorized 16B stores
      unsigned short* sC = smem;  // 128 x 136
#pragma unroll
      for (int i = 0; i < 4; ++i) {
        const int lr0 = wm + i * 16 + quad * 4;
#pragma unroll
        for (int j = 0; j < 4; ++j) {
          const int lc = wn + j * 16 + l16;
          const float bb = bias[n0 + lc];
#pragma unroll
          for (int r = 0; r < 4; ++r) sC[(lr0 + r) * 136 + lc] = f2bf(acc[i][j][r] + bb);
        }
      }
      __syncthreads();
      unsigned short* Out = (z == 0) ? Qb : Kb;
      const int rr = tid >> 4, c8 = (tid & 15) * 8;
#pragma unroll
      for (int it = 0; it < 8; ++it) {
        const int row = it * 16 + rr;
        *(uint4*)&Out[(size_t)(m0 + row) * DD + n0 + c8] = *(const uint4*)&sC[row * 136 + c8];
      }
    } else {
      // transposed staging: sC[dv-local][s-local], then 256B-contiguous row stores
      unsigned short* sC = smem;  // 128 x 136
#pragma unroll
      for (int i = 0; i < 4; ++i) {
        const int lr0 = wm + i * 16 + quad * 4;   // s-local
#pragma unroll
        for (int j = 0; j < 4; ++j) {
          const int lc = wn + j * 16 + l16;       // dv-local (n)
          const float bb = bias[n0 + lc];
#pragma unroll
          for (int r = 0; r < 4; ++r) sC[lc * 136 + lr0 + r] = f2bf(acc[i][j][r] + bb);
        }
      }
      __syncthreads();
      const int b = m0 >> 10, s0 = m0 & 1023;
      const int rr = tid >> 4, c8 = (tid & 15) * 8;
#pragma unroll
      for (int it = 0; it < 8; ++it) {
        const int row = it * 16 + rr;  // dv-local
        const int n = n0 + row;
        unsigned short* dst =
            &Vt[((size_t)((b * HH + (n >> 6)) * 64 + (n & 63))) * SS + s0 + c8];
        *(uint4*)dst = *(const uint4*)&sC[row * 136 + c8];
      }
    }
    __syncthreads();  // sC reads must finish before next rep's stage overwrites smem
  }
}

// ---------- fused attention: per (b,h,q-tile 64) ----------
// Production (r10, PASSED 412.5us): QBLK=64, KVBLK=64, 1024 blocks, LDS 32 KB.
// SWAPPED QK^T + in-register P via cvtpk + dbuf K/V prefetch + setprio.
__global__ __launch_bounds__(256) void attn_kernel(
    const unsigned short* __restrict__ Qb, const unsigned short* __restrict__ Kb,
    const unsigned short* __restrict__ Vt, const float* __restrict__ X,
    const int* __restrict__ lens, float* __restrict__ seq_out,
    float* __restrict__ attn_out) {
  __shared__ __align__(16) unsigned short smem[4 * 64 * 64];  // 32 KB
  unsigned short* const sK0 = smem;            // 8 KB  K buf 0
  unsigned short* const sK1 = smem + 4096;     // 8 KB  K buf 1
  unsigned short* const sV0 = smem + 8192;     // 8 KB  Q tile, then V buf 0
  unsigned short* const sV1 = smem + 12288;    // 8 KB  V buf 1

  const int tid = threadIdx.x;
  const int lane = tid & 63, wv = tid >> 6;
  const int quad = lane >> 4, l16 = lane & 15;
  const int h = blockIdx.y, b = blockIdx.z;
  const int qt = (b & 2) ? (15 - (int)blockIdx.x) : (int)blockIdx.x;
  const int q0 = qt * 64;
  const int len = lens[b];
  const int KE = min(q0 + 64, len);
  const int NKT = (KE + 63) >> 6;
  const float SCL = 0.1803368801111204f;  // 0.125 * log2(e)
  const int s7 = l16 & 7;                 // row&7 for 64-short rows (row = ..+l16)

  auto stageK = [&](int k0, unsigned short* dst) {
#pragma unroll
    for (int it = 0; it < 2; ++it) {
      const int c = it * 256 + tid;
      const int row = c >> 3, ch = (c & 7) ^ (row & 7);
      async16(Kb + (size_t)(b * SS + k0 + row) * DD + h * 64 + ch * 8,
              &dst[(it * 256 + wv * 64) * 8]);
    }
  };
  auto stageV = [&](int k0, unsigned short* dst) {
#pragma unroll
    for (int it = 0; it < 2; ++it) {
      const int c = it * 256 + tid;
      const int row = c >> 3, ch = (c & 7) ^ (row & 7);  // row = dv 0..63, 8 chunks
      async16(Vt + ((size_t)((b * HH + h) * 64 + row)) * SS + k0 + ch * 8,
              &dst[(it * 256 + wv * 64) * 8]);
    }
  };

  // ---- prologue: stage Q (into sV0) and K tile 0 ----
#pragma unroll
  for (int it = 0; it < 2; ++it) {
    const int c = it * 256 + tid;
    const int row = c >> 3, ch = (c & 7) ^ (row & 7);
    async16(Qb + (size_t)(b * SS + q0 + row) * DD + h * 64 + ch * 8,
            &sV0[(it * 256 + wv * 64) * 8]);
  }
  stageK(0, sK0);
  __syncthreads();

  bf16x8 qf[2];
#pragma unroll
  for (int dd = 0; dd < 2; ++dd)
    qf[dd] = *(const bf16x8*)
        &sV0[(wv * 16 + l16) * 64 + ((dd * 4 + quad) ^ s7) * 8];

  // ---- pass 1: denominators (lane sums its 4 k's for q row = q0+wv*16+l16) ----
  float lsum = 0.f;
  int par = 0;

  for (int kt = 0; kt < NKT; ++kt) {
    const int k0 = kt * 64;
    const int nxt = par ^ 1;
    unsigned short* const Kcur = par ? sK1 : sK0;
    if (kt + 1 < NKT) {
      stageK((kt + 1) * 64, nxt ? sK1 : sK0);
    } else {  // prefetch pass-2 tile 0
      stageK(0, nxt ? sK1 : sK0);
      stageV(0, nxt ? sV1 : sV0);
    }
    const bool edge = (kt == qt) || (k0 + 64 > len);
    const int qq = q0 + wv * 16 + l16;
#pragma unroll
    for (int j = 0; j < 4; ++j) {
      const bf16x8 kf0 = *(const bf16x8*)&Kcur[(j * 16 + l16) * 64 + ((0 + quad) ^ s7) * 8];
      const bf16x8 kf1 = *(const bf16x8*)&Kcur[(j * 16 + l16) * 64 + ((4 + quad) ^ s7) * 8];
      const int kb = k0 + j * 16 + quad * 4;
      f32x4 sc = (f32x4){0.f, 0.f, 0.f, 0.f};
      __builtin_amdgcn_s_setprio(1);
      sc = mfma16(kf0, qf[0], sc);
      sc = mfma16(kf1, qf[1], sc);
      __builtin_amdgcn_s_setprio(0);
#pragma unroll
      for (int r = 0; r < 4; ++r) {
        float sv = sc[r] * SCL;
        if (edge && ((kb + r > qq) || (kb + r >= len))) sv = -1e30f;
        lsum += __builtin_amdgcn_exp2f(sv);
      }
    }
    __syncthreads();
    par = nxt;
  }

  float linv;
  {
    float l = lsum;
    l += __shfl_xor(l, 16);
    l += __shfl_xor(l, 32);
    linv = 1.0f / l;
  }

  // ---- pass 2 ----
  f32x4 oacc[4];
#pragma unroll
  for (int jv = 0; jv < 4; ++jv) oacc[jv] = (f32x4){0.f, 0.f, 0.f, 0.f};

  const size_t abase = (size_t)(b * HH + h) * SS * SS;
  float* const arow = attn_out + abase + (size_t)(q0 + wv * 16 + l16) * SS;

  for (int kt = 0; kt < NKT; ++kt) {
    const int k0 = kt * 64;
    const int nxt = par ^ 1;
    unsigned short* const Kcur = par ? sK1 : sK0;
    unsigned short* const Vcur = par ? sV1 : sV0;
    if (kt + 1 < NKT) {
      stageK((kt + 1) * 64, nxt ? sK1 : sK0);
      stageV((kt + 1) * 64, nxt ? sV1 : sV0);
    }
    const bool edge = (kt == qt) || (k0 + 64 > len);
    const int qq = q0 + wv * 16 + l16;

    uint32_t afw[2][4];  // [kk][word] — PV A-fragment words, built in-register
#pragma unroll
    for (int j = 0; j < 4; ++j) {
      const bf16x8 kf0 = *(const bf16x8*)&Kcur[(j * 16 + l16) * 64 + ((0 + quad) ^ s7) * 8];
      const bf16x8 kf1 = *(const bf16x8*)&Kcur[(j * 16 + l16) * 64 + ((4 + quad) ^ s7) * 8];
      const int kb = k0 + j * 16 + quad * 4;
      f32x4 sc = (f32x4){0.f, 0.f, 0.f, 0.f};
      __builtin_amdgcn_s_setprio(1);
      sc = mfma16(kf0, qf[0], sc);
      sc = mfma16(kf1, qf[1], sc);
      __builtin_amdgcn_s_setprio(0);
      f32x4 p;
#pragma unroll
      for (int r = 0; r < 4; ++r) {
        float sv = sc[r] * SCL;
        if (edge && ((kb + r > qq) || (kb + r >= len))) sv = -1e30f;
        p[r] = __builtin_amdgcn_exp2f(sv) * linv;
      }
      nt_store4(arow + kb, p);
      afw[j >> 1][(j & 1) * 2 + 0] = cvtpk(p[0], p[1]);
      afw[j >> 1][(j & 1) * 2 + 1] = cvtpk(p[2], p[3]);
    }

    // PV: O += P (16x64) * V (64x64), per wave; P already in registers.
#pragma unroll
    for (int kk = 0; kk < 2; ++kk) {
      union { bf16x8 v8; bf16x4 v4[2]; } vfu[4];
      const int g1 = kk * 4 + (quad >> 1);       // kv chunk of run 1 (0..7)
      const int boff = (quad & 1) * 8;           // byte offset within chunk
#pragma unroll
      for (int jv = 0; jv < 4; ++jv) {
        const char* rowp = (const char*)(Vcur + (jv * 16 + l16) * 64);
        vfu[jv].v4[0] = *(const bf16x4*)(rowp + ((g1 ^ s7) * 16 + boff));
        vfu[jv].v4[1] = *(const bf16x4*)(rowp + (((g1 + 2) ^ s7) * 16 + boff));
      }
      union { uint32_t w[4]; bf16x8 v8; } pu;
      pu.w[0] = afw[kk][0];
      pu.w[1] = afw[kk][1];
      pu.w[2] = afw[kk][2];
      pu.w[3] = afw[kk][3];
      __builtin_amdgcn_s_setprio(1);
#pragma unroll
      for (int jv = 0; jv < 4; ++jv) oacc[jv] = mfma16(pu.v8, vfu[jv].v8, oacc[jv]);
      __builtin_amdgcn_s_setprio(0);
    }
    __syncthreads();
    par = nxt;
  }

  // zero-fill fully-masked column range [NKT*64, S)
  const int Z = SS - NKT * 64;
  if (Z > 0) {
    const int rr0 = tid >> 3;
    const int cf = (tid & 7) * 4;
    const f32x4 zz = (f32x4){0.f, 0.f, 0.f, 0.f};
    for (int rr = rr0; rr < 64; rr += 32) {
      float* dst = attn_out + abase + (size_t)(q0 + rr) * SS + NKT * 64 + cf;
      for (int c8 = 0; c8 < (Z >> 5); ++c8) nt_store4(dst + c8 * 32, zz);
    }
  }

  // epilogue: stage O in LDS (fp32, reuse smem), then seq = x + O via float4
  __syncthreads();
  {
    float* sPf = (float*)smem + wv * 1024;  // 4 KB per wave, 16 KB total
#pragma unroll
    for (int jv = 0; jv < 4; ++jv)
#pragma unroll
      for (int r = 0; r < 4; ++r)
        sPf[(quad * 4 + r) * 64 + jv * 16 + l16] = oacc[jv][r];
    const int rr = lane >> 4, c4 = (lane & 15) * 4;
#pragma unroll
    for (int it = 0; it < 4; ++it) {
      const int lrow = it * 4 + rr;
      const size_t idx = (size_t)(b * SS + q0 + wv * 16 + lrow) * DD + h * 64 + c4;
      float4 o = *(const float4*)&sPf[lrow * 64 + c4];
      float4 x = *(const float4*)&X[idx];
      o.x += x.x; o.y += x.y; o.z += x.z; o.w += x.w;
      *(float4*)&seq_out[idx] = o;
    }
  }
}

extern "C" void kernel_launch(void* const* d_in, const int* in_sizes, int n_in,
                              void* d_out, int out_size, void* d_ws, size_t ws_size,
                              hipStream_t stream) {
  (void)in_sizes; (void)n_in; (void)out_size; (void)ws_size;
  const float* X     = (const float*)d_in[0];
  const int*   lens  = (const int*)d_in[3];
  const float* gamma = (const float*)d_in[4];
  const float* beta  = (const float*)d_in[5];
  const float* Wq    = (const float*)d_in[6];
  const float* bq    = (const float*)d_in[7];
  const float* Wk    = (const float*)d_in[8];
  const float* bk    = (const float*)d_in[9];
  const float* Wv    = (const float*)d_in[10];
  const float* bv    = (const float*)d_in[11];

  // workspace layout (38 MB total)
  char* ws = (char*)d_ws;
  unsigned short* Xn  = (unsigned short*)(ws);                      // 8 MB
  unsigned short* Qb  = (unsigned short*)(ws + ((size_t)8  << 20)); // 8 MB
  unsigned short* Kb  = (unsigned short*)(ws + ((size_t)16 << 20)); // 8 MB
  unsigned short* Vt  = (unsigned short*)(ws + ((size_t)24 << 20)); // 8 MB  (B*H*64, S)
  unsigned short* Wtq = (unsigned short*)(ws + ((size_t)32 << 20)); // 2 MB
  unsigned short* Wtk = (unsigned short*)(ws + ((size_t)34 << 20)); // 2 MB
  unsigned short* Wtv = (unsigned short*)(ws + ((size_t)36 << 20)); // 2 MB

  float* seq_out  = (float*)d_out;                         // (B,S,1024)
  float* attn_out = seq_out + (size_t)BB * SS * DD;        // (B,H,S,S)

  wtrans_kernel<<<dim3(16, 16, 3), 256, 0, stream>>>(Wq, Wk, Wv, Wtq, Wtk, Wtv);
  ln_kernel<<<dim3(BB * SS), 256, 0, stream>>>(X, gamma, beta, Xn);
  gemm_qkv_kernel<<<dim3(32, 8, 3), 256, 0, stream>>>(Xn, Wtq, Wtk, Wtv, bq, bk, bv, Qb, Kb, Vt);
  attn_kernel<<<dim3(16, HH, BB), 256, 0, stream>>>(Qb, Kb, Vt, X, lens, seq_out, attn_out);
}

// Round 16
// 401.048 us; speedup vs baseline: 1.5572x; 1.4245x over previous
//
#include <hip/hip_runtime.h>
#include <stdint.h>

#define BB 4
#define SS 1024
#define DD 1024
#define HH 16

typedef __attribute__((ext_vector_type(8))) __bf16 bf16x8;
typedef __attribute__((ext_vector_type(4))) __bf16 bf16x4;
typedef __attribute__((ext_vector_type(4))) float f32x4;

__device__ __forceinline__ unsigned short f2bf(float f) {
  union { float ff; uint32_t u; } a; a.ff = f;
  uint32_t r = a.u + 0x7fffu + ((a.u >> 16) & 1u);
  return (unsigned short)(r >> 16);
}

__device__ __forceinline__ float bf2f(unsigned short u) {
  union { uint32_t uu; float ff; } a; a.uu = ((uint32_t)u) << 16;
  return a.ff;
}

__device__ __forceinline__ f32x4 mfma16(bf16x8 a, bf16x8 b, f32x4 c) {
  return __builtin_amdgcn_mfma_f32_16x16x32_bf16(a, b, c, 0, 0, 0);
}

// pack two fp32 -> packed bf16x2 (lo = a, hi = b), RNE
__device__ __forceinline__ uint32_t cvtpk(float a, float b) {
  uint32_t r;
  asm("v_cvt_pk_bf16_f32 %0, %1, %2" : "=v"(r) : "v"(a), "v"(b));
  return r;
}

// global -> LDS direct copy, 16B per lane; LDS dest is wave-uniform base + lane*16
__device__ __forceinline__ void async16(const unsigned short* g, unsigned short* l) {
  __builtin_amdgcn_global_load_lds(
      (__attribute__((address_space(1))) void*)(g),
      (__attribute__((address_space(3))) void*)(l), 16u, 0, 0u);
}

// nontemporal 16B store — must use clang ext_vector_type, not HIP float4 class
__device__ __forceinline__ void nt_store4(float* p, f32x4 v) {
  __builtin_nontemporal_store(v, (f32x4*)p);
}

// ---------- W (K x N fp32) -> Wt (N x K bf16), z selects which of Q/K/V ----------
__global__ __launch_bounds__(256) void wtrans_kernel(const float* __restrict__ Wq,
                                                     const float* __restrict__ Wk,
                                                     const float* __restrict__ Wv,
                                                     unsigned short* __restrict__ Wtq,
                                                     unsigned short* __restrict__ Wtk,
                                                     unsigned short* __restrict__ Wtv) {
  __shared__ unsigned short t[64][65];
  const int z = blockIdx.z;
  const float* W = (z == 0) ? Wq : (z == 1) ? Wk : Wv;
  unsigned short* Wt = (z == 0) ? Wtq : (z == 1) ? Wtk : Wtv;
  const int k0 = blockIdx.x * 64, n0 = blockIdx.y * 64;
  const int c = threadIdx.x & 63, r0 = threadIdx.x >> 6;
#pragma unroll
  for (int i = 0; i < 16; ++i) {
    int r = i * 4 + r0;
    t[r][c] = f2bf(W[(size_t)(k0 + r) * DD + n0 + c]);
  }
  __syncthreads();
#pragma unroll
  for (int i = 0; i < 16; ++i) {
    int n = i * 4 + r0;
    Wt[(size_t)(n0 + n) * DD + k0 + c] = t[c][n];
  }
}

// ---------- LayerNorm (fp32 math) -> bf16 ----------
__global__ __launch_bounds__(256) void ln_kernel(const float* __restrict__ X,
                                                 const float* __restrict__ gamma,
                                                 const float* __restrict__ beta,
                                                 unsigned short* __restrict__ Xn) {
  const int row = blockIdx.x;
  const int tid = threadIdx.x;
  const float* xr = X + (size_t)row * DD;
  float4 v = ((const float4*)xr)[tid];
  float s = v.x + v.y + v.z + v.w;
  float s2 = v.x * v.x + v.y * v.y + v.z * v.z + v.w * v.w;
#pragma unroll
  for (int off = 1; off < 64; off <<= 1) {
    s += __shfl_xor(s, off);
    s2 += __shfl_xor(s2, off);
  }
  __shared__ float red[8];
  const int wv = tid >> 6, lane = tid & 63;
  if (lane == 0) { red[wv] = s; red[4 + wv] = s2; }
  __syncthreads();
  s = red[0] + red[1] + red[2] + red[3];
  s2 = red[4] + red[5] + red[6] + red[7];
  const float mu = s * (1.0f / DD);
  const float rs = rsqrtf(s2 * (1.0f / DD) - mu * mu + 1e-5f);
  float4 g = ((const float4*)gamma)[tid];
  float4 bt = ((const float4*)beta)[tid];
  ushort4 o;
  o.x = f2bf((v.x - mu) * rs * g.x + bt.x);
  o.y = f2bf((v.y - mu) * rs * g.y + bt.y);
  o.z = f2bf((v.z - mu) * rs * g.z + bt.z);
  o.w = f2bf((v.w - mu) * rs * g.w + bt.w);
  ((ushort4*)(Xn + (size_t)row * DD))[tid] = o;
}

// ---------- QKV GEMM: C = Xn (M x K) * Wt^T (Wt is N x K), 128x128 tile ----------
// Double-buffered staging: stage kt+32 before computing kt, ONE barrier per K-step.
// __launch_bounds__(256,3): cap VGPR at 170 -> 3 waves/SIMD -> 3 blocks/CU
// (r15 counters: 180 VGPR / 2 blocks/CU / MfmaUtil 19% -> occupancy-bound).
__global__ __launch_bounds__(256, 3) void gemm_qkv_kernel(
    const unsigned short* __restrict__ Xn,
    const unsigned short* __restrict__ Wtq, const unsigned short* __restrict__ Wtk,
    const unsigned short* __restrict__ Wtv,
    const float* __restrict__ bq, const float* __restrict__ bk, const float* __restrict__ bv,
    unsigned short* __restrict__ Qb, unsigned short* __restrict__ Kb,
    unsigned short* __restrict__ Vt) {
  // union: dbuf [sA|sB]x2 (32 KB) during K-loop, sC 128x136 (34.8 KB) in epilogue
  __shared__ __align__(16) unsigned short smem[128 * 136];
  unsigned short* const sA0 = smem;
  unsigned short* const sB0 = smem + 4096;
  unsigned short* const sA1 = smem + 8192;
  unsigned short* const sB1 = smem + 12288;
  const int z = blockIdx.z;
  const unsigned short* Wt = (z == 0) ? Wtq : (z == 1) ? Wtk : Wtv;
  const float* bias = (z == 0) ? bq : (z == 1) ? bk : bv;
  const int tid = threadIdx.x;
  const int lane = tid & 63, wv = tid >> 6;
  const int quad = lane >> 4, l16 = lane & 15;
  const int m0 = blockIdx.x * 128, n0 = blockIdx.y * 128;
  const int wm = (wv & 1) * 64, wn = (wv >> 1) * 64;

  f32x4 acc[4][4];
#pragma unroll
  for (int i = 0; i < 4; ++i)
#pragma unroll
    for (int j = 0; j < 4; ++j) acc[i][j] = (f32x4){0.f, 0.f, 0.f, 0.f};

  auto stage = [&](int kt, unsigned short* sA, unsigned short* sB) {
#pragma unroll
    for (int it = 0; it < 2; ++it) {
      const int c = it * 256 + tid;
      const int row = c >> 2, kc = c & 3;
      async16(Xn + (size_t)(m0 + row) * DD + kt + kc * 8, &sA[(it * 256 + wv * 64) * 8]);
      async16(Wt + (size_t)(n0 + row) * DD + kt + kc * 8, &sB[(it * 256 + wv * 64) * 8]);
    }
  };

  stage(0, sA0, sB0);
  __syncthreads();

  for (int kt = 0; kt < DD; kt += 32) {
    const int par = (kt >> 5) & 1;
    unsigned short* const sA = par ? sA1 : sA0;
    unsigned short* const sB = par ? sB1 : sB0;
    if (kt + 32 < DD) stage(kt + 32, par ? sA0 : sA1, par ? sB0 : sB1);
    bf16x8 af[4], bfr[4];
#pragma unroll
    for (int i = 0; i < 4; ++i) af[i] = *(const bf16x8*)&sA[(wm + i * 16 + l16) * 32 + quad * 8];
#pragma unroll
    for (int j = 0; j < 4; ++j) bfr[j] = *(const bf16x8*)&sB[(wn + j * 16 + l16) * 32 + quad * 8];
#pragma unroll
    for (int i = 0; i < 4; ++i)
#pragma unroll
      for (int j = 0; j < 4; ++j) acc[i][j] = mfma16(af[i], bfr[j], acc[i][j]);
    __syncthreads();
  }

  if (z < 2) {
    // stage C tile (bf16) in padded LDS, then vectorized 16B stores
    unsigned short* sC = smem;  // 128 x 136
#pragma unroll
    for (int i = 0; i < 4; ++i) {
      const int lr0 = wm + i * 16 + quad * 4;
#pragma unroll
      for (int j = 0; j < 4; ++j) {
        const int lc = wn + j * 16 + l16;
        const float bb = bias[n0 + lc];
#pragma unroll
        for (int r = 0; r < 4; ++r) sC[(lr0 + r) * 136 + lc] = f2bf(acc[i][j][r] + bb);
      }
    }
    __syncthreads();
    unsigned short* Out = (z == 0) ? Qb : Kb;
    const int rr = tid >> 4, c8 = (tid & 15) * 8;
#pragma unroll
    for (int it = 0; it < 8; ++it) {
      const int row = it * 16 + rr;
      *(uint4*)&Out[(size_t)(m0 + row) * DD + n0 + c8] = *(const uint4*)&sC[row * 136 + c8];
    }
  } else {
    // transposed staging: sC[dv-local][s-local], then 256B-contiguous row stores
    unsigned short* sC = smem;  // 128 x 136
#pragma unroll
    for (int i = 0; i < 4; ++i) {
      const int lr0 = wm + i * 16 + quad * 4;   // s-local
#pragma unroll
      for (int j = 0; j < 4; ++j) {
        const int lc = wn + j * 16 + l16;       // dv-local (n)
        const float bb = bias[n0 + lc];
#pragma unroll
        for (int r = 0; r < 4; ++r) sC[lc * 136 + lr0 + r] = f2bf(acc[i][j][r] + bb);
      }
    }
    __syncthreads();
    const int b = m0 >> 10, s0 = m0 & 1023;
    const int rr = tid >> 4, c8 = (tid & 15) * 8;
#pragma unroll
    for (int it = 0; it < 8; ++it) {
      const int row = it * 16 + rr;  // dv-local
      const int n = n0 + row;
      unsigned short* dst =
          &Vt[((size_t)((b * HH + (n >> 6)) * 64 + (n & 63))) * SS + s0 + c8];
      *(uint4*)dst = *(const uint4*)&sC[row * 136 + c8];
    }
  }
}

// ---------- fused attention: per (b,h,q-tile 64) ----------
// Production (r10, PASSED 412.5us): QBLK=64, KVBLK=64, 1024 blocks, LDS 32 KB.
// SWAPPED QK^T + in-register P via cvtpk + dbuf K/V prefetch + setprio.
// r14 counters: hbm 66% peak (BW-bound on mandated 256MB attn_out) — near floor.
__global__ __launch_bounds__(256) void attn_kernel(
    const unsigned short* __restrict__ Qb, const unsigned short* __restrict__ Kb,
    const unsigned short* __restrict__ Vt, const float* __restrict__ X,
    const int* __restrict__ lens, float* __restrict__ seq_out,
    float* __restrict__ attn_out) {
  __shared__ __align__(16) unsigned short smem[4 * 64 * 64];  // 32 KB
  unsigned short* const sK0 = smem;            // 8 KB  K buf 0
  unsigned short* const sK1 = smem + 4096;     // 8 KB  K buf 1
  unsigned short* const sV0 = smem + 8192;     // 8 KB  Q tile, then V buf 0
  unsigned short* const sV1 = smem + 12288;    // 8 KB  V buf 1

  const int tid = threadIdx.x;
  const int lane = tid & 63, wv = tid >> 6;
  const int quad = lane >> 4, l16 = lane & 15;
  const int h = blockIdx.y, b = blockIdx.z;
  const int qt = (b & 2) ? (15 - (int)blockIdx.x) : (int)blockIdx.x;
  const int q0 = qt * 64;
  const int len = lens[b];
  const int KE = min(q0 + 64, len);
  const int NKT = (KE + 63) >> 6;
  const float SCL = 0.1803368801111204f;  // 0.125 * log2(e)
  const int s7 = l16 & 7;                 // row&7 for 64-short rows (row = ..+l16)

  auto stageK = [&](int k0, unsigned short* dst) {
#pragma unroll
    for (int it = 0; it < 2; ++it) {
      const int c = it * 256 + tid;
      const int row = c >> 3, ch = (c & 7) ^ (row & 7);
      async16(Kb + (size_t)(b * SS + k0 + row) * DD + h * 64 + ch * 8,
              &dst[(it * 256 + wv * 64) * 8]);
    }
  };
  auto stageV = [&](int k0, unsigned short* dst) {
#pragma unroll
    for (int it = 0; it < 2; ++it) {
      const int c = it * 256 + tid;
      const int row = c >> 3, ch = (c & 7) ^ (row & 7);  // row = dv 0..63, 8 chunks
      async16(Vt + ((size_t)((b * HH + h) * 64 + row)) * SS + k0 + ch * 8,
              &dst[(it * 256 + wv * 64) * 8]);
    }
  };

  // ---- prologue: stage Q (into sV0) and K tile 0 ----
#pragma unroll
  for (int it = 0; it < 2; ++it) {
    const int c = it * 256 + tid;
    const int row = c >> 3, ch = (c & 7) ^ (row & 7);
    async16(Qb + (size_t)(b * SS + q0 + row) * DD + h * 64 + ch * 8,
            &sV0[(it * 256 + wv * 64) * 8]);
  }
  stageK(0, sK0);
  __syncthreads();

  bf16x8 qf[2];
#pragma unroll
  for (int dd = 0; dd < 2; ++dd)
    qf[dd] = *(const bf16x8*)
        &sV0[(wv * 16 + l16) * 64 + ((dd * 4 + quad) ^ s7) * 8];

  // ---- pass 1: denominators (lane sums its 4 k's for q row = q0+wv*16+l16) ----
  float lsum = 0.f;
  int par = 0;

  for (int kt = 0; kt < NKT; ++kt) {
    const int k0 = kt * 64;
    const int nxt = par ^ 1;
    unsigned short* const Kcur = par ? sK1 : sK0;
    if (kt + 1 < NKT) {
      stageK((kt + 1) * 64, nxt ? sK1 : sK0);
    } else {  // prefetch pass-2 tile 0
      stageK(0, nxt ? sK1 : sK0);
      stageV(0, nxt ? sV1 : sV0);
    }
    const bool edge = (kt == qt) || (k0 + 64 > len);
    const int qq = q0 + wv * 16 + l16;
#pragma unroll
    for (int j = 0; j < 4; ++j) {
      const bf16x8 kf0 = *(const bf16x8*)&Kcur[(j * 16 + l16) * 64 + ((0 + quad) ^ s7) * 8];
      const bf16x8 kf1 = *(const bf16x8*)&Kcur[(j * 16 + l16) * 64 + ((4 + quad) ^ s7) * 8];
      const int kb = k0 + j * 16 + quad * 4;
      f32x4 sc = (f32x4){0.f, 0.f, 0.f, 0.f};
      __builtin_amdgcn_s_setprio(1);
      sc = mfma16(kf0, qf[0], sc);
      sc = mfma16(kf1, qf[1], sc);
      __builtin_amdgcn_s_setprio(0);
#pragma unroll
      for (int r = 0; r < 4; ++r) {
        float sv = sc[r] * SCL;
        if (edge && ((kb + r > qq) || (kb + r >= len))) sv = -1e30f;
        lsum += __builtin_amdgcn_exp2f(sv);
      }
    }
    __syncthreads();
    par = nxt;
  }

  float linv;
  {
    float l = lsum;
    l += __shfl_xor(l, 16);
    l += __shfl_xor(l, 32);
    linv = 1.0f / l;
  }

  // ---- pass 2 ----
  f32x4 oacc[4];
#pragma unroll
  for (int jv = 0; jv < 4; ++jv) oacc[jv] = (f32x4){0.f, 0.f, 0.f, 0.f};

  const size_t abase = (size_t)(b * HH + h) * SS * SS;
  float* const arow = attn_out + abase + (size_t)(q0 + wv * 16 + l16) * SS;

  for (int kt = 0; kt < NKT; ++kt) {
    const int k0 = kt * 64;
    const int nxt = par ^ 1;
    unsigned short* const Kcur = par ? sK1 : sK0;
    unsigned short* const Vcur = par ? sV1 : sV0;
    if (kt + 1 < NKT) {
      stageK((kt + 1) * 64, nxt ? sK1 : sK0);
      stageV((kt + 1) * 64, nxt ? sV1 : sV0);
    }
    const bool edge = (kt == qt) || (k0 + 64 > len);
    const int qq = q0 + wv * 16 + l16;

    uint32_t afw[2][4];  // [kk][word] — PV A-fragment words, built in-register
#pragma unroll
    for (int j = 0; j < 4; ++j) {
      const bf16x8 kf0 = *(const bf16x8*)&Kcur[(j * 16 + l16) * 64 + ((0 + quad) ^ s7) * 8];
      const bf16x8 kf1 = *(const bf16x8*)&Kcur[(j * 16 + l16) * 64 + ((4 + quad) ^ s7) * 8];
      const int kb = k0 + j * 16 + quad * 4;
      f32x4 sc = (f32x4){0.f, 0.f, 0.f, 0.f};
      __builtin_amdgcn_s_setprio(1);
      sc = mfma16(kf0, qf[0], sc);
      sc = mfma16(kf1, qf[1], sc);
      __builtin_amdgcn_s_setprio(0);
      f32x4 p;
#pragma unroll
      for (int r = 0; r < 4; ++r) {
        float sv = sc[r] * SCL;
        if (edge && ((kb + r > qq) || (kb + r >= len))) sv = -1e30f;
        p[r] = __builtin_amdgcn_exp2f(sv) * linv;
      }
      nt_store4(arow + kb, p);
      afw[j >> 1][(j & 1) * 2 + 0] = cvtpk(p[0], p[1]);
      afw[j >> 1][(j & 1) * 2 + 1] = cvtpk(p[2], p[3]);
    }

    // PV: O += P (16x64) * V (64x64), per wave; P already in registers.
#pragma unroll
    for (int kk = 0; kk < 2; ++kk) {
      union { bf16x8 v8; bf16x4 v4[2]; } vfu[4];
      const int g1 = kk * 4 + (quad >> 1);       // kv chunk of run 1 (0..7)
      const int boff = (quad & 1) * 8;           // byte offset within chunk
#pragma unroll
      for (int jv = 0; jv < 4; ++jv) {
        const char* rowp = (const char*)(Vcur + (jv * 16 + l16) * 64);
        vfu[jv].v4[0] = *(const bf16x4*)(rowp + ((g1 ^ s7) * 16 + boff));
        vfu[jv].v4[1] = *(const bf16x4*)(rowp + (((g1 + 2) ^ s7) * 16 + boff));
      }
      union { uint32_t w[4]; bf16x8 v8; } pu;
      pu.w[0] = afw[kk][0];
      pu.w[1] = afw[kk][1];
      pu.w[2] = afw[kk][2];
      pu.w[3] = afw[kk][3];
      __builtin_amdgcn_s_setprio(1);
#pragma unroll
      for (int jv = 0; jv < 4; ++jv) oacc[jv] = mfma16(pu.v8, vfu[jv].v8, oacc[jv]);
      __builtin_amdgcn_s_setprio(0);
    }
    __syncthreads();
    par = nxt;
  }

  // zero-fill fully-masked column range [NKT*64, S)
  const int Z = SS - NKT * 64;
  if (Z > 0) {
    const int rr0 = tid >> 3;
    const int cf = (tid & 7) * 4;
    const f32x4 zz = (f32x4){0.f, 0.f, 0.f, 0.f};
    for (int rr = rr0; rr < 64; rr += 32) {
      float* dst = attn_out + abase + (size_t)(q0 + rr) * SS + NKT * 64 + cf;
      for (int c8 = 0; c8 < (Z >> 5); ++c8) nt_store4(dst + c8 * 32, zz);
    }
  }

  // epilogue: stage O in LDS (fp32, reuse smem), then seq = x + O via float4
  __syncthreads();
  {
    float* sPf = (float*)smem + wv * 1024;  // 4 KB per wave, 16 KB total
#pragma unroll
    for (int jv = 0; jv < 4; ++jv)
#pragma unroll
      for (int r = 0; r < 4; ++r)
        sPf[(quad * 4 + r) * 64 + jv * 16 + l16] = oacc[jv][r];
    const int rr = lane >> 4, c4 = (lane & 15) * 4;
#pragma unroll
    for (int it = 0; it < 4; ++it) {
      const int lrow = it * 4 + rr;
      const size_t idx = (size_t)(b * SS + q0 + wv * 16 + lrow) * DD + h * 64 + c4;
      float4 o = *(const float4*)&sPf[lrow * 64 + c4];
      float4 x = *(const float4*)&X[idx];
      o.x += x.x; o.y += x.y; o.z += x.z; o.w += x.w;
      *(float4*)&seq_out[idx] = o;
    }
  }
}

extern "C" void kernel_launch(void* const* d_in, const int* in_sizes, int n_in,
                              void* d_out, int out_size, void* d_ws, size_t ws_size,
                              hipStream_t stream) {
  (void)in_sizes; (void)n_in; (void)out_size; (void)ws_size;
  const float* X     = (const float*)d_in[0];
  const int*   lens  = (const int*)d_in[3];
  const float* gamma = (const float*)d_in[4];
  const float* beta  = (const float*)d_in[5];
  const float* Wq    = (const float*)d_in[6];
  const float* bq    = (const float*)d_in[7];
  const float* Wk    = (const float*)d_in[8];
  const float* bk    = (const float*)d_in[9];
  const float* Wv    = (const float*)d_in[10];
  const float* bv    = (const float*)d_in[11];

  // workspace layout (38 MB total)
  char* ws = (char*)d_ws;
  unsigned short* Xn  = (unsigned short*)(ws);                      // 8 MB
  unsigned short* Qb  = (unsigned short*)(ws + ((size_t)8  << 20)); // 8 MB
  unsigned short* Kb  = (unsigned short*)(ws + ((size_t)16 << 20)); // 8 MB
  unsigned short* Vt  = (unsigned short*)(ws + ((size_t)24 << 20)); // 8 MB  (B*H*64, S)
  unsigned short* Wtq = (unsigned short*)(ws + ((size_t)32 << 20)); // 2 MB
  unsigned short* Wtk = (unsigned short*)(ws + ((size_t)34 << 20)); // 2 MB
  unsigned short* Wtv = (unsigned short*)(ws + ((size_t)36 << 20)); // 2 MB

  float* seq_out  = (float*)d_out;                         // (B,S,1024)
  float* attn_out = seq_out + (size_t)BB * SS * DD;        // (B,H,S,S)

  wtrans_kernel<<<dim3(16, 16, 3), 256, 0, stream>>>(Wq, Wk, Wv, Wtq, Wtk, Wtv);
  ln_kernel<<<dim3(BB * SS), 256, 0, stream>>>(X, gamma, beta, Xn);
  gemm_qkv_kernel<<<dim3(32, 8, 3), 256, 0, stream>>>(Xn, Wtq, Wtk, Wtv, bq, bk, bv, Qb, Kb, Vt);
  attn_kernel<<<dim3(16, HH, BB), 256, 0, stream>>>(Qb, Kb, Vt, X, lens, seq_out, attn_out);
}